// Round 1
// baseline (268.977 us; speedup 1.0000x reference)
//
#include <hip/hip_runtime.h>

#define DT 0.001f

typedef float f4 __attribute__((ext_vector_type(4)));

// DPP row_ror ring all-reduce within each aligned group of 16 lanes.
template<int CTRL>
__device__ __forceinline__ float dpp_add(float v) {
    int r = __builtin_amdgcn_update_dpp(0, __float_as_int(v), CTRL, 0xf, 0xf, false);
    return v + __int_as_float(r);
}

__device__ __forceinline__ float reduce16(float t) {
    t = dpp_add<0x121>(t);  // row_ror:1
    t = dpp_add<0x122>(t);  // row_ror:2
    t = dpp_add<0x124>(t);  // row_ror:4
    t = dpp_add<0x128>(t);  // row_ror:8
    return t;
}

__device__ __forceinline__ float sumsq(const f4 a) {
    return (a.x * a.x + a.y * a.y) + (a.z * a.z + a.w * a.w);
}
__device__ __forceinline__ float dot4(const f4 a, const f4 b) {
    return (a.x * b.x + a.y * b.y) + (a.z * b.z + a.w * b.w);
}

// Steady state: the whole Nose-Hoover scalar dynamics (alpha, scale factors,
// Sum v^2) is advanced via a scalar second-moment recurrence; the (x,v)
// vectors are evolved once per chunk through the accumulated 2x2 linear map.
// Critical path per step: 9 dependent scalar FMAs, no cross-lane ops.
template<int SE>
__device__ __forceinline__ void run(
    f4& x, f4& u, float& sv, float& al_mcE,
    float& Sxx, float& Sxv, float& Svv,
    int n_chunks, int se_rt,
    float c, float c2, float c2E,
    float A11, float A21,
    float A11sq, float A11A21, float A212, float TWOA11, float TWOA21,
    float Ph1, float Ph2, float Pf1, float Pf2, float kc1, float kc2,
    f4* outx, f4* outv, int snap4, int fidx)
{
    const int se = (SE > 0) ? SE : se_rt;
    // cumulative Verlet+scale map for this chunk: (x,u) -> M*(x,u)
    float m00 = 1.f, m01 = 0.f, m10 = 0.f, m11 = 1.f;
    float q0 = A11, q1 = 0.f, p0 = A21, p1 = 0.f;   // A11*row0, A21*row0 of M
    float e0 = A212 * Sxx, e1 = TWOA21 * Sxv;       // r(d) = e0 + e1*d + Svv*d^2
    for (int ck = 1; ck <= n_chunks; ++ck) {
        #pragma unroll
        for (int i = 0; i < se - 1; ++i) {
            const float b = sv * DT;
            const float d = sv * A11;               // A22 == A11
            // post-kick Sum v^2 via moment quadratic (critical path)
            const float r  = __builtin_fmaf(d, __builtin_fmaf(d, Svv, e1), e0);
            const float a3 = __builtin_fmaf(c, r, al_mcE);                    // U3
            const float k0 = __builtin_fmaf(c2, r, -c2E);
            const float k1 = __builtin_fmaf(r, kc1, 1.0f);
            const float k2 = r * kc2;
            const float a4 = __builtin_fmaf(a3, __builtin_fmaf(a3, k2, k1), k0); // U4+U1
            const float w  = a3 + a4;
            const float svn = __builtin_fmaf(w, __builtin_fmaf(w, Ph2, Ph1), 1.0f); // s2*s1
            const float sv2 = svn * svn;
            const float cr  = c * r;
            al_mcE = __builtin_fmaf(cr, sv2, a4 - c2E);                       // U2 - cE
            // cumulative 2x2 map update (off critical path)
            const float n00 = __builtin_fmaf(b, m10, q0);
            const float n01 = __builtin_fmaf(b, m11, q1);
            const float n10 = __builtin_fmaf(d, m10, p0);
            const float n11 = __builtin_fmaf(d, m11, p1);
            m00 = n00; m01 = n01; m10 = n10; m11 = n11;
            q0 = A11 * m00; q1 = A11 * m01;
            p0 = A21 * m00; p1 = A21 * m01;
            // second-moment advance (off critical path); Svv' = r for free
            const float bb = b * b, bd = b * d;
            const float tb = TWOA11 * b;
            const float mid = __builtin_fmaf(A21, b, A11 * d);
            const float nSxx = __builtin_fmaf(bb, Svv,
                                __builtin_fmaf(tb, Sxv, A11sq * Sxx));
            const float nSxv = __builtin_fmaf(bd, Svv,
                                __builtin_fmaf(mid, Sxv, A11A21 * Sxx));
            Sxx = nSxx; Sxv = nSxv; Svv = r;
            e0 = A212 * Sxx; e1 = TWOA21 * Sxv;
            sv = svn;
        }
        // ---- chunk-final step: materialize vectors, snapshot, refresh ----
        {
            const float b = sv * DT;
            const float d = sv * A11;
            const float r  = __builtin_fmaf(d, __builtin_fmaf(d, Svv, e1), e0);
            const float n00 = __builtin_fmaf(b, m10, q0);
            const float n01 = __builtin_fmaf(b, m11, q1);
            const float n10 = __builtin_fmaf(d, m10, p0);
            const float n11 = __builtin_fmaf(d, m11, p1);
            const float a3 = __builtin_fmaf(c, r, al_mcE);                    // U3
            const float s2  = __builtin_fmaf(a3, __builtin_fmaf(a3, Ph2, Ph1), 1.0f);
            const float s2q = __builtin_fmaf(a3, __builtin_fmaf(a3, Pf2, Pf1), 1.0f);
            f4 xe = n00 * x + n01 * u;          // true x after se steps
            f4 ue = n10 * x + n11 * u;          // post-kick v, pre-S2
            f4 vs = s2 * ue;                    // snapshot v (S2 applied; U4 leaves v)
            __builtin_nontemporal_store(xe, &outx[(size_t)ck * snap4 + fidx]);
            __builtin_nontemporal_store(vs, &outv[(size_t)ck * snap4 + fidx]);
            // moment refresh from real vectors (bounds recurrence drift to 1 chunk)
            const float Rxx = reduce16(sumsq(xe));
            const float Rxv = reduce16(dot4(xe, vs));
            const float Rvv = reduce16(sumsq(vs));
            const float r2 = r * s2q;
            const float a4 = __builtin_fmaf(c2, r2, a3 - c2E);                // U4+U1(next)
            const float s1  = __builtin_fmaf(a4, __builtin_fmaf(a4, Ph2, Ph1), 1.0f);
            const float s1q = __builtin_fmaf(a4, __builtin_fmaf(a4, Pf2, Pf1), 1.0f);
            const float r3 = r2 * s1q;
            al_mcE = __builtin_fmaf(c, r3, a4 - c2E);                         // U2(next) - cE
            sv = s1;
            x = xe; u = vs;
            Sxx = Rxx; Sxv = Rxv; Svv = Rvv;
            e0 = A212 * Sxx; e1 = TWOA21 * Sxv;
            m00 = 1.f; m01 = 0.f; m10 = 0.f; m11 = 1.f;
            q0 = A11; q1 = 0.f; p0 = A21; p1 = 0.f;
        }
    }
}

__global__ __launch_bounds__(256) void nh_kernel(
    const float* __restrict__ x0, const float* __restrict__ v0,
    const float* __restrict__ alpha0,
    const float* __restrict__ kT_p, const float* __restrict__ mass_p,
    const float* __restrict__ Q_p,
    const int* __restrict__ n_steps_p, const int* __restrict__ store_every_p,
    float* __restrict__ out, int B)
{
    const int D = 64;
    const int gid = blockIdx.x * blockDim.x + threadIdx.x;
    const int sys = gid >> 4;   // 16 lanes per system
    const int g   = gid & 15;   // lane holds elems [4g..4g+3]
    if (sys >= B) return;

    const int n_steps = *n_steps_p;
    const int se      = *store_every_p;
    const int n_chunks = n_steps / se;

    const float kt = *kT_p, m = *mass_p, q = *Q_p;
    const float c   = 0.25f * DT / q;
    const float E   = (float)D * kt;
    const float cE  = c * E;
    const float c2  = 2.0f * c;
    const float c2E = 2.0f * cE;
    const float hd  = 0.5f * DT / m;
    const float hdt = 0.5f * DT;

    // kick-drift-kick is linear for f = -x:  x' = A11*x + DT*v ; v' = A21*x + A11*v
    const float A11 = 1.0f - hd * DT;
    const float A21 = -hd * (2.0f - hd * DT);
    const float A11sq  = A11 * A11;
    const float A11A21 = A11 * A21;
    const float A212   = A21 * A21;
    const float TWOA11 = 2.0f * A11;
    const float TWOA21 = 2.0f * A21;
    // exp(-hdt*a) ~= 1 + Ph1*a + Ph2*a^2 ; exp(-DT*a) ~= 1 + Pf1*a + Pf2*a^2
    // (|hdt*a| ~ 5e-5: degree-2 error ~z^3/6 ~ 1e-13, far below f32 eps)
    const float Ph1 = -hdt, Ph2 = 0.5f * hdt * hdt;
    const float Pf1 = -DT,  Pf2 = 0.5f * DT * DT;
    // U4+U1 flattening: a4 = k0 + k1*a3 + k2*a3^2, k's linear in r
    const float kc1 = -c2 * DT;
    const float kc2 = 0.5f * c2 * DT * DT;

    const int snap4 = B * 16;
    const int fidx  = sys * 16 + g;

    f4 x = ((const f4*)x0)[fidx];
    f4 v = ((const f4*)v0)[fidx];
    const float al0 = alpha0[sys];

    f4* outx = (f4*)out;
    f4* outv = ((f4*)out) + (size_t)(n_chunks + 1) * snap4;

    // snapshot 0
    __builtin_nontemporal_store(x, &outx[fidx]);
    __builtin_nontemporal_store(v, &outv[fidx]);

    // initial second moments
    float Svv = reduce16(sumsq(v));
    float Sxx = reduce16(sumsq(x));
    float Sxv = reduce16(dot4(x, v));

    // head of step 1: U1, S1 (scale deferred into first Verlet), U2
    const float a1  = __builtin_fmaf(c, Svv, al0 - cE);                       // U1
    const float s1  = __builtin_fmaf(a1, __builtin_fmaf(a1, Ph2, Ph1), 1.0f);
    const float s1q = __builtin_fmaf(a1, __builtin_fmaf(a1, Pf2, Pf1), 1.0f);
    float sv = s1;
    const float r1 = Svv * s1q;
    float al_mcE = __builtin_fmaf(c, r1, a1 - c2E);                           // U2 - cE
    f4 u = v;

    if (se == 10)
        run<10>(x, u, sv, al_mcE, Sxx, Sxv, Svv, n_chunks, se, c, c2, c2E,
                A11, A21, A11sq, A11A21, A212, TWOA11, TWOA21,
                Ph1, Ph2, Pf1, Pf2, kc1, kc2, outx, outv, snap4, fidx);
    else
        run<0>(x, u, sv, al_mcE, Sxx, Sxv, Svv, n_chunks, se, c, c2, c2E,
               A11, A21, A11sq, A11A21, A212, TWOA11, TWOA21,
               Ph1, Ph2, Pf1, Pf2, kc1, kc2, outx, outv, snap4, fidx);
}

extern "C" void kernel_launch(void* const* d_in, const int* in_sizes, int n_in,
                              void* d_out, int out_size, void* d_ws, size_t ws_size,
                              hipStream_t stream) {
    const float* x0     = (const float*)d_in[0];
    const float* v0     = (const float*)d_in[1];
    const float* alpha0 = (const float*)d_in[2];
    const float* kT     = (const float*)d_in[3];
    const float* mass   = (const float*)d_in[4];
    const float* Q      = (const float*)d_in[5];
    const int* n_steps  = (const int*)d_in[6];
    const int* store_ev = (const int*)d_in[7];

    const int B = in_sizes[0] / 64;       // D = 64
    const int threads = B * 16;
    const int block = 256;
    const int grid = (threads + block - 1) / block;

    nh_kernel<<<grid, block, 0, stream>>>(x0, v0, alpha0, kT, mass, Q,
                                          n_steps, store_ev, (float*)d_out, B);
}

// Round 3
// 256.597 us; speedup vs baseline: 1.0482x; 1.0482x over previous
//
#include <hip/hip_runtime.h>

#define DT 0.001f

typedef float f4 __attribute__((ext_vector_type(4)));

// DPP row_ror ring all-reduce within each aligned group of 16 lanes.
template<int CTRL>
__device__ __forceinline__ float dpp_add(float v) {
    int r = __builtin_amdgcn_update_dpp(0, __float_as_int(v), CTRL, 0xf, 0xf, false);
    return v + __int_as_float(r);
}

__device__ __forceinline__ float reduce16(float t) {
    t = dpp_add<0x121>(t);  // row_ror:1
    t = dpp_add<0x122>(t);  // row_ror:2
    t = dpp_add<0x124>(t);  // row_ror:4
    t = dpp_add<0x128>(t);  // row_ror:8
    return t;
}

__device__ __forceinline__ float sumsq(const f4 a) {
    return (a.x * a.x + a.y * a.y) + (a.z * a.z + a.w * a.w);
}
__device__ __forceinline__ float dot4(const f4 a, const f4 b) {
    return (a.x * b.x + a.y * b.y) + (a.z * b.z + a.w * b.w);
}

// Steady state: scalar Nose-Hoover dynamics (alpha, scale sv) advanced via the
// running 2x2 Verlet+scale map M; post-kick Sum v^2 comes from the quadratic
// form r = n10^2*Sxx0 + 2*n10*n11*Sxv0 + n11^2*Svv0 against chunk-start
// moments. 28 VALU ops / step (was 38), no cross-lane ops in steady state.
template<int SE>
__device__ __forceinline__ void run(
    f4& x, f4& u, float& sv, float& alm,
    float Sxx0, float tSxv0, float Svv0,
    int n_chunks, int se_rt,
    float c, float c2, float cE, float c2E, float M2C2E,
    float A11, float A21,
    float G00, float G01, float G10, float G11, float G2P,
    float kc1, float kc2,
    float Ph1, float Ph2, float Pf1, float Pf2,
    f4* outx, f4* outv, int snap4, int fidx)
{
    const int se = (SE > 0) ? SE : se_rt;
    // cumulative map: (x,u)_chunkstart -> current (x, v_prescale); q/p = A11/A21 * row0
    float m00 = 1.f, m01 = 0.f, m10 = 0.f, m11 = 1.f;
    float q0 = A11, q1 = 0.f, p0 = A21, p1 = 0.f;
    for (int ck = 1; ck <= n_chunks; ++ck) {
        #pragma unroll
        for (int i = 0; i < se - 1; ++i) {
            const float b = sv * DT;
            const float d = sv * A11;               // A22 == A11
            const float n00 = __builtin_fmaf(b, m10, q0);
            const float n01 = __builtin_fmaf(b, m11, q1);
            const float n10 = __builtin_fmaf(d, m10, p0);
            const float n11 = __builtin_fmaf(d, m11, p1);
            // post-kick Sum v^2 as quadratic form of map row 1
            const float u1 = __builtin_fmaf(tSxv0, n11, Sxx0 * n10);
            const float r  = __builtin_fmaf(Svv0, n11 * n11, n10 * u1);
            const float a3 = __builtin_fmaf(c, r, alm);                    // U3
            // svn = s2*s1 = exp(-hdt*(a3+a4)) as quadratic in a3, coeffs linear in r
            const float g0 = __builtin_fmaf(G01, r, G00);
            const float g1 = __builtin_fmaf(G11, r, G10);
            const float svn = __builtin_fmaf(a3, __builtin_fmaf(a3, G2P, g1), g0);
            // a4m = alpha_after_U1 - c2E (U4+U1 fused, quadratic in a3)
            const float k0m = __builtin_fmaf(c2, r, M2C2E);
            const float k1  = __builtin_fmaf(kc1, r, 1.0f);
            const float k2  = kc2 * r;
            const float a4m = __builtin_fmaf(a3, __builtin_fmaf(a3, k2, k1), k0m);
            alm = __builtin_fmaf(c * r, svn * svn, a4m);                   // U2 - cE
            m00 = n00; m01 = n01; m10 = n10; m11 = n11;
            q0 = A11 * n00; q1 = A11 * n01;
            p0 = A21 * n00; p1 = A21 * n01;
            sv = svn;
        }
        // ---- chunk-final step: materialize vectors, snapshot, refresh ----
        {
            const float b = sv * DT;
            const float d = sv * A11;
            const float n00 = __builtin_fmaf(b, m10, q0);
            const float n01 = __builtin_fmaf(b, m11, q1);
            const float n10 = __builtin_fmaf(d, m10, p0);
            const float n11 = __builtin_fmaf(d, m11, p1);
            const float u1 = __builtin_fmaf(tSxv0, n11, Sxx0 * n10);
            const float r  = __builtin_fmaf(Svv0, n11 * n11, n10 * u1);
            const float a3 = __builtin_fmaf(c, r, alm);                    // U3
            const float s2  = __builtin_fmaf(a3, __builtin_fmaf(a3, Ph2, Ph1), 1.0f);
            const float s2q = __builtin_fmaf(a3, __builtin_fmaf(a3, Pf2, Pf1), 1.0f);
            f4 xe = n00 * x + n01 * u;          // true x after se steps
            f4 ue = n10 * x + n11 * u;          // post-kick v, pre-S2
            f4 vs = s2 * ue;                    // snapshot v (S2 applied; U4 leaves v)
            __builtin_nontemporal_store(xe, &outx[(size_t)ck * snap4 + fidx]);
            __builtin_nontemporal_store(vs, &outv[(size_t)ck * snap4 + fidx]);
            // moment refresh from real vectors (bounds recurrence drift to 1 chunk)
            const float Rxx = reduce16(sumsq(xe));
            const float Rxv = reduce16(dot4(xe, vs));
            const float Rvv = reduce16(sumsq(vs));
            const float r2  = r * s2q;                                     // Sum v^2 post-S2
            const float aU4 = __builtin_fmaf(c, r2, a3 - cE);              // U4
            const float aU1 = __builtin_fmaf(c, Rvv, aU4 - cE);            // U1 (next step)
            const float s1  = __builtin_fmaf(aU1, __builtin_fmaf(aU1, Ph2, Ph1), 1.0f);
            const float s1q = __builtin_fmaf(aU1, __builtin_fmaf(aU1, Pf2, Pf1), 1.0f);
            alm = __builtin_fmaf(c * Rvv, s1q, aU1 - c2E);                 // U2(next) - cE
            sv = s1;
            x = xe; u = vs;
            Sxx0 = Rxx; tSxv0 = 2.0f * Rxv; Svv0 = Rvv;
            m00 = 1.f; m01 = 0.f; m10 = 0.f; m11 = 1.f;
            q0 = A11; q1 = 0.f; p0 = A21; p1 = 0.f;
        }
    }
}

__global__ __launch_bounds__(256) void nh_kernel(
    const float* __restrict__ x0, const float* __restrict__ v0,
    const float* __restrict__ alpha0,
    const float* __restrict__ kT_p, const float* __restrict__ mass_p,
    const float* __restrict__ Q_p,
    const int* __restrict__ n_steps_p, const int* __restrict__ store_every_p,
    float* __restrict__ out, int B)
{
    const int D = 64;
    const int gid = blockIdx.x * blockDim.x + threadIdx.x;
    const int sys = gid >> 4;   // 16 lanes per system
    const int g   = gid & 15;   // lane holds elems [4g..4g+3]
    if (sys >= B) return;

    const int n_steps = *n_steps_p;
    const int se      = *store_every_p;
    const int n_chunks = n_steps / se;

    const float kt = *kT_p, m = *mass_p, q = *Q_p;
    const float c   = 0.25f * DT / q;
    const float E   = (float)D * kt;
    const float cE  = c * E;
    const float c2  = 2.0f * c;
    const float c2E = 2.0f * cE;
    const float M2C2E = -2.0f * c2E;
    const float hd  = 0.5f * DT / m;
    const float hdt = 0.5f * DT;

    // kick-drift-kick is linear for f = -x:  x' = A11*x + DT*v ; v' = A21*x + A11*v
    const float A11 = 1.0f - hd * DT;
    const float A21 = -hd * (2.0f - hd * DT);
    // exp(-hdt*a) ~= 1 + Ph1*a + Ph2*a^2 ; exp(-DT*a) ~= 1 + Pf1*a + Pf2*a^2
    const float Ph1 = -hdt, Ph2 = 0.5f * hdt * hdt;
    const float Pf1 = -DT,  Pf2 = 0.5f * DT * DT;
    // U4+U1 fusion: a4 = k0 + (1 + kc1*r)*a3 + kc2*r*a3^2
    const float kc1 = -c2 * DT;
    const float kc2 = 0.5f * c2 * DT * DT;
    // svn = exp(-hdt*(a3+a4)) = g0(r) + g1(r)*a3 + G2P*a3^2  (negligible terms dropped)
    const float G00 = 1.0f - Ph1 * c2E;
    const float G01 = Ph1 * c2;
    const float G10 = 2.0f * Ph1;
    const float G11 = Ph1 * kc1;
    const float G2P = 4.0f * Ph2;

    const int snap4 = B * 16;
    const int fidx  = sys * 16 + g;

    f4 x = ((const f4*)x0)[fidx];
    f4 v = ((const f4*)v0)[fidx];
    const float al0 = alpha0[sys];

    f4* outx = (f4*)out;
    f4* outv = ((f4*)out) + (size_t)(n_chunks + 1) * snap4;

    // snapshot 0
    __builtin_nontemporal_store(x, &outx[fidx]);
    __builtin_nontemporal_store(v, &outv[fidx]);

    // initial second moments
    float Svv = reduce16(sumsq(v));
    float Sxx = reduce16(sumsq(x));
    float Sxv = reduce16(dot4(x, v));

    // head of step 1: U1, S1 (scale deferred into first map update), U2
    const float a1  = __builtin_fmaf(c, Svv, al0 - cE);                       // U1
    const float s1  = __builtin_fmaf(a1, __builtin_fmaf(a1, Ph2, Ph1), 1.0f);
    const float s1q = __builtin_fmaf(a1, __builtin_fmaf(a1, Pf2, Pf1), 1.0f);
    float sv = s1;
    const float r1 = Svv * s1q;
    float alm = __builtin_fmaf(c, r1, a1 - c2E);                              // U2 - cE
    f4 u = v;

    if (se == 10)
        run<10>(x, u, sv, alm, Sxx, 2.0f * Sxv, Svv, n_chunks, se,
                c, c2, cE, c2E, M2C2E, A11, A21,
                G00, G01, G10, G11, G2P, kc1, kc2,
                Ph1, Ph2, Pf1, Pf2, outx, outv, snap4, fidx);
    else
        run<0>(x, u, sv, alm, Sxx, 2.0f * Sxv, Svv, n_chunks, se,
               c, c2, cE, c2E, M2C2E, A11, A21,
               G00, G01, G10, G11, G2P, kc1, kc2,
               Ph1, Ph2, Pf1, Pf2, outx, outv, snap4, fidx);
}

extern "C" void kernel_launch(void* const* d_in, const int* in_sizes, int n_in,
                              void* d_out, int out_size, void* d_ws, size_t ws_size,
                              hipStream_t stream) {
    const float* x0     = (const float*)d_in[0];
    const float* v0     = (const float*)d_in[1];
    const float* alpha0 = (const float*)d_in[2];
    const float* kT     = (const float*)d_in[3];
    const float* mass   = (const float*)d_in[4];
    const float* Q      = (const float*)d_in[5];
    const int* n_steps  = (const int*)d_in[6];
    const int* store_ev = (const int*)d_in[7];

    const int B = in_sizes[0] / 64;       // D = 64
    const int threads = B * 16;
    const int block = 256;
    const int grid = (threads + block - 1) / block;

    nh_kernel<<<grid, block, 0, stream>>>(x0, v0, alpha0, kT, mass, Q,
                                          n_steps, store_ev, (float*)d_out, B);
}